// Round 19
// baseline (273.481 us; speedup 1.0000x reference)
//
#include <hip/hip_runtime.h>
#include <hip/hip_bf16.h>

typedef __hip_bfloat16 bf16;
typedef float f32x4 __attribute__((ext_vector_type(4)));
typedef short bf16x8 __attribute__((ext_vector_type(8)));
typedef _Float16 f16x2 __attribute__((ext_vector_type(2)));

#define HW 65536
#define NB 8

__device__ __forceinline__ bf16 f2b(float v){ return __float2bfloat16(v); }
__device__ __forceinline__ float b2f(bf16 v){ return __bfloat162float(v); }
__device__ __forceinline__ unsigned short fbits(float v){ bf16 b = f2b(v); return *(unsigned short*)&b; }
__device__ __forceinline__ unsigned int pk2(float a, float b){
    return (unsigned int)fbits(a) | ((unsigned int)fbits(b) << 16);
}
__device__ __forceinline__ float dot2h(f16x2 a, f16x2 b, float c){
#if __has_builtin(__builtin_amdgcn_fdot2)
    return __builtin_amdgcn_fdot2(a, b, c, false);
#else
    return c + (float)a[0]*(float)b[0] + (float)a[1]*(float)b[1];
#endif
}

// single merged pack kernel:
//  [0, 110592)          conv3 A-pack -> Bp3
//  [110592, 131072)     conv2 A-pack -> Bp2
//  [131072, 131936)     tail c1/c2 f16 pairing
__global__ void pack_all(const float* __restrict__ fxw2, const float* __restrict__ fgw2,
                         const float* __restrict__ fxw3, const float* __restrict__ fgw3,
                         const float* __restrict__ c1w,  const float* __restrict__ c2w,
                         short* __restrict__ Bp2, short* __restrict__ Bp3,
                         f16x2* __restrict__ c1wp, f16x2* __restrict__ c2wp)
{
    int idx = blockIdx.x * 256 + threadIdx.x;
    if (idx < 110592) {
        int unit = idx >> 9, r = idx & 511;
        int lane = r >> 3, j = r & 7;
        int mt = unit % 6; int u2 = unit / 6;
        int ks = u2 % 9;  int u3 = u2 / 9;
        int half = u3 & 1, br = u3 >> 1;
        int n = mt * 16 + (lane & 15);
        int c = half * 32 + ((lane >> 4) << 3) + j;
        const float* w = br ? fgw3 : fxw3;
        Bp3[idx] = fbits((n < 81) ? w[n * 576 + c * 9 + ks] : 0.f);
    } else if (idx < 131072) {
        int i = idx - 110592;
        int unit = i >> 9, r = i & 511;
        int lane = r >> 3, j = r & 7;
        int mt2 = unit & 1; int u2 = unit >> 1;
        int ks = u2 % 5; int u3 = u2 / 5;
        int half = u3 & 1, br = u3 >> 1;
        int n = half * 32 + mt2 * 16 + (lane & 15);
        int k = ks * 32 + ((lane >> 4) << 3) + j;
        int tap = k >> 4, c16 = k & 15;
        const float* w = br ? fgw2 : fxw2;
        Bp2[i] = fbits((tap < 9) ? w[n * 144 + c16 * 9 + tap] : 0.f);
    } else if (idx < 131936) {
        int i = idx - 131072;
        if (i < 576) {
            int c = i / 9, q = i - c * 9;
            c1wp[i] = (f16x2){(_Float16)c1w[c * 18 + q], (_Float16)c1w[c * 18 + 9 + q]};
        } else {
            int k = i - 576;
            int t9 = k >> 5, cp = k & 31;
            c2wp[k] = (f16x2){(_Float16)c2w[(2 * cp) * 9 + t9], (_Float16)c2w[(2 * cp + 1) * 9 + t9]};
        }
    }
}

__global__ void s_kernel(const float* __restrict__ out0, const float* __restrict__ d,
                         float* __restrict__ s)
{
    int i = blockIdx.x * 256 + threadIdx.x;
    s[i] = out0[i] - d[i];
}

// One dyn-filter branch per block: 16x16 output tile, 512 threads (8 waves).
// == R16 with h1 stride reverted 24->16 (measured conflict series: stride16
// kernels had 7.5-10.7M conflicts, stride24 13.7M, swizzle 21.9M — both
// "fixes" hurt). No swizzle, no setprio. No-max softmax kept (R15->R16 win).
// NOTE: no 2nd launch_bounds arg (R8/R13 mis-capped VGPRs).
__global__ __launch_bounds__(512) void branch_kernel(
    const float* __restrict__ origin, const float* __restrict__ residual,
    const float* __restrict__ fxw1, const float* __restrict__ fxb1,
    const float* __restrict__ fxb2, const float* __restrict__ fxb3,
    const float* __restrict__ fgw1, const float* __restrict__ fgb1,
    const float* __restrict__ fgb2, const float* __restrict__ fgb3,
    const short* __restrict__ Bp2, const short* __restrict__ Bp3,
    bf16* __restrict__ pack, float* __restrict__ dout)
{
    __shared__ bf16 s_srcb[648];      // 24x24 bf16 + 72 pad (gather never clamps)
    __shared__ bf16 s_h1[6720];       // [420 px][16ch], rows 400..419 zero (pads)
    __shared__ bf16 s_h2[12960];      // [324 px][40] ch-last (32 used, current half)
    __shared__ float s_sm2[1024];     // [mg][row16][col16][2] partial (ssum,fsum)

    const int t = threadIdx.x;
    const int lane = t & 63;
    const int w = t >> 6;             // wave 0..7
    const int mg = w >> 2;            // m-group: taps 48*mg..48*mg+47
    const int ng = w & 3;             // n-group: rows 4*ng..4*ng+3
    const int mt0 = 3 * mg;
    const int g = lane >> 4;
    const int j16 = lane & 15;
    const int tile = blockIdx.x;
    const int br = blockIdx.y >> 3;
    const int img = blockIdx.y & 7;
    const int y0 = (tile >> 4) << 4, x0 = (tile & 15) << 4;
    const long ib = (long)img * HW;

    const float* w1 = br ? fgw1 : fxw1;
    const float* b1 = br ? fgb1 : fxb1;
    const float* b2 = br ? fgb2 : fxb2;
    const float* b3 = br ? fgb3 : fxb3;

    // ---- phase 1: stage src (bf16, 648 incl. pad); g-branch materializes d ----
    for (int idx = t; idx < 648; idx += 512) {
        int sy = idx / 24, sx = idx - sy * 24;
        int gy = y0 - 4 + sy, gx = x0 - 4 + sx;
        float v = 0.f;
        if ((unsigned)gy < 256u && (unsigned)gx < 256u && idx < 576) {
            long o = ib + (gy << 8) + gx;
            if (br) { v = origin[o] - residual[o]; dout[o] = v; }
            else    { v = residual[o]; }
        }
        s_srcb[idx] = f2b(v);
    }
    __syncthreads();

    // ---- phase 2: conv1 (1->16) VALU -> h1 ch-last (stride 16); zero pad rows ----
    if (t < 400) {
        int p = t;
        int py = p / 20, px = p - py * 20;
        int gy = y0 - 2 + py, gx = x0 - 2 + px;
        bool in = (unsigned)gy < 256u && (unsigned)gx < 256u;
        float sw[9];
        #pragma unroll
        for (int dy = 0; dy < 3; dy++)
            #pragma unroll
            for (int dx = 0; dx < 3; dx++)
                sw[dy * 3 + dx] = b2f(s_srcb[(py + 1 + dy) * 24 + px + 1 + dx]);
        #pragma unroll
        for (int c = 0; c < 16; c++) {
            float a = b1[c];
            const float* wc = w1 + c * 9;
            #pragma unroll
            for (int q = 0; q < 9; q++) a = fmaf(wc[q], sw[q], a);
            s_h1[p * 16 + c] = f2b(in ? fmaxf(a, 0.f) : 0.f);
        }
    }
    for (int idx = t; idx < 320; idx += 512)
        s_h1[6400 + idx] = f2b(0.f);

    // ---- logits acc[3 m-tiles][4 n-tiles]; lane: taps (mt0+mi)*16+g*4+r, px (4ng+nr, j16) ----
    f32x4 acc[3][4];
    #pragma unroll
    for (int mi = 0; mi < 3; mi++) {
        int mt = mt0 + mi;
        f32x4 bv;
        if (mt < 5) {
            bv = *(const f32x4*)&b3[mt * 16 + (g << 2)];
        } else {
            float e0 = (g == 0) ? b3[80] : -1e30f;
            bv = (f32x4){e0, -1e30f, -1e30f, -1e30f};
        }
        #pragma unroll
        for (int nr = 0; nr < 4; nr++) acc[mi][nr] = bv;
    }
    __syncthreads();

    // ---- phases 3/4 per 32-channel half ----
    for (int h = 0; h < 2; h++) {
        // conv2: D[ch][px]; A=weights, B=h1 pixels. 21 n-tiles over 8 waves
        {
            const short* Aw2 = Bp2 + (br * 2 + h) * 5120;
            bf16x8 A2[5][2];
            #pragma unroll
            for (int ks = 0; ks < 5; ks++)
                #pragma unroll
                for (int mt2 = 0; mt2 < 2; mt2++)
                    A2[ks][mt2] = *(const bf16x8*)(Aw2 + ((ks * 2 + mt2) << 9) + lane * 8);
            const int kgh = g >> 1, c0 = (g & 1) * 8;
            for (int nt = w; nt < 21; nt += 8) {
                int p = nt * 16 + j16;
                int py = p / 18, px = p - py * 18;
                f32x4 acc2[2];
                #pragma unroll
                for (int mt2 = 0; mt2 < 2; mt2++)
                    acc2[mt2] = *(const f32x4*)&b2[h * 32 + mt2 * 16 + (g << 2)];
                #pragma unroll
                for (int ks = 0; ks < 5; ks++) {
                    int tap = 2 * ks + kgh;
                    int ty = (tap * 11) >> 5;
                    int tx = tap - ty * 3;
                    int pl = (py + ty) * 20 + px + tx;   // <=419, pad rows zeroed
                    bf16x8 B = *(const bf16x8*)&s_h1[pl * 16 + c0];
                    #pragma unroll
                    for (int mt2 = 0; mt2 < 2; mt2++)
                        acc2[mt2] = __builtin_amdgcn_mfma_f32_16x16x32_bf16(A2[ks][mt2], B, acc2[mt2], 0, 0, 0);
                }
                if (p < 324) {
                    #pragma unroll
                    for (int mt2 = 0; mt2 < 2; mt2++) {
                        unsigned int lo = pk2(fmaxf(acc2[mt2][0], 0.f), fmaxf(acc2[mt2][1], 0.f));
                        unsigned int hi = pk2(fmaxf(acc2[mt2][2], 0.f), fmaxf(acc2[mt2][3], 0.f));
                        *(uint2*)((char*)s_h2 + (p * 40 + mt2 * 16 + (g << 2)) * 2) = (uint2){lo, hi};
                    }
                }
            }
        }
        __syncthreads();

        // conv3: D[tap][px]; wave does its 3 m-tiles x 4 n-tiles. A 1-deep prefetch.
        {
            const short* Aw3 = Bp3 + (br * 2 + h) * 27648;
            bf16x8 Acur[3], Anxt[3];
            #pragma unroll
            for (int mi = 0; mi < 3; mi++)
                Acur[mi] = *(const bf16x8*)(Aw3 + ((mt0 + mi) << 9) + lane * 8);
            #pragma unroll
            for (int ks = 0; ks < 9; ks++) {
                const int dy = (ks * 11) >> 5;
                const int dx = ks - dy * 3;
                if (ks < 8) {
                    #pragma unroll
                    for (int mi = 0; mi < 3; mi++)
                        Anxt[mi] = *(const bf16x8*)(Aw3 + (((ks + 1) * 6 + mt0 + mi) << 9) + lane * 8);
                }
                bf16x8 Bf[4];
                #pragma unroll
                for (int nr = 0; nr < 4; nr++) {
                    int pl = (4 * ng + nr + dy) * 18 + j16 + dx;
                    Bf[nr] = *(const bf16x8*)&s_h2[pl * 40 + (g << 3)];
                }
                #pragma unroll
                for (int mi = 0; mi < 3; mi++)
                    #pragma unroll
                    for (int nr = 0; nr < 4; nr++)
                        acc[mi][nr] = __builtin_amdgcn_mfma_f32_16x16x32_bf16(Acur[mi], Bf[nr], acc[mi][nr], 0, 0, 0);
                #pragma unroll
                for (int mi = 0; mi < 3; mi++) Acur[mi] = Anxt[mi];
            }
        }
        __syncthreads();
    }

    // ---- phase 5: softmax (NO max-pass) over 96 taps, split across 2 m-groups ----
    int toff[3][4];
    #pragma unroll
    for (int mi = 0; mi < 3; mi++)
        #pragma unroll
        for (int r = 0; r < 4; r++) {
            int tap = (mt0 + mi) * 16 + (g << 2) + r;
            int ti = (tap * 57) >> 9;                // tap/9 for tap<96
            toff[mi][r] = ti * 24 + (tap - ti * 9);
        }

    #pragma unroll
    for (int nr = 0; nr < 4; nr++) {
        int rb = (4 * ng + nr) * 16 + j16;
        float ss = 0.f, fs = 0.f;
        int base = (4 * ng + nr) * 24 + j16;
        #pragma unroll
        for (int mi = 0; mi < 3; mi++)
            #pragma unroll
            for (int r = 0; r < 4; r++) {
                float e = __expf(acc[mi][nr][r]);    // pads (-1e30) -> 0
                ss += e;
                fs += e * b2f(s_srcb[base + toff[mi][r]]);
            }
        ss += __shfl_xor(ss, 16);
        ss += __shfl_xor(ss, 32);
        fs += __shfl_xor(fs, 16);
        fs += __shfl_xor(fs, 32);
        if (g == 0) {
            s_sm2[(mg * 256 + rb) * 2]     = ss;
            s_sm2[(mg * 256 + rb) * 2 + 1] = fs;
        }
    }
    __syncthreads();

    // combine + store: waves 0..3 (mg==0), lane (g,j16) -> row 4*ng+g
    if (mg == 0) {
        int row = (ng << 2) + g;
        int rb = row * 16 + j16;
        float s0 = s_sm2[rb * 2],           f0 = s_sm2[rb * 2 + 1];
        float s1 = s_sm2[(256 + rb) * 2],   f1 = s_sm2[(256 + rb) * 2 + 1];
        pack[((long)(img * 2 + br) << 16) + ((y0 + row) << 8) + x0 + j16] = f2b((f0 + f1) / (s0 + s1));
    }
}

// c1(2->64)+c2(64->1) fused per tile via fp16 dot2; out0 = s + d
__global__ __launch_bounds__(256) void tail_kernel(
    const bf16* __restrict__ pack,
    const f16x2* __restrict__ c1wp, const float* __restrict__ c1b,
    const f16x2* __restrict__ c2wp, const float* __restrict__ c2b,
    const float* __restrict__ d2, float* __restrict__ out0)
{
    __shared__ f16x2 s_xg[400];            // 20x20 of (x_, g_)
    __shared__ _Float16 s_h[22680];        // [324][70] (64 used)

    const int t = threadIdx.x;
    const int tile = blockIdx.x;
    const int img = blockIdx.y;
    const int y0 = (tile >> 4) << 4, x0 = (tile & 15) << 4;

    for (int idx = t; idx < 400; idx += 256) {
        int hy = idx / 20, hx = idx - hy * 20;
        int gy = y0 - 2 + hy, gx = x0 - 2 + hx;
        float vx = 0.f, vg = 0.f;
        if ((unsigned)gy < 256u && (unsigned)gx < 256u) {
            int o = (gy << 8) + gx;
            vx = b2f(pack[((img * 2 + 0) << 16) + o]);
            vg = b2f(pack[((img * 2 + 1) << 16) + o]);
        }
        s_xg[idx] = (f16x2){(_Float16)vx, (_Float16)vg};
    }
    __syncthreads();

    for (int p = t; p < 324; p += 256) {
        int hy = p / 18, hx = p - hy * 18;
        int gy = y0 - 1 + hy, gx = x0 - 1 + hx;
        bool in = (unsigned)gy < 256u && (unsigned)gx < 256u;
        f16x2 sw[9];
        #pragma unroll
        for (int dy = 0; dy < 3; dy++)
            #pragma unroll
            for (int dx = 0; dx < 3; dx++)
                sw[dy * 3 + dx] = s_xg[(hy + dy) * 20 + hx + dx];
        for (int c = 0; c < 64; c++) {
            float a = c1b[c];
            const f16x2* wp = c1wp + c * 9;
            #pragma unroll
            for (int q = 0; q < 9; q++) a = dot2h(sw[q], wp[q], a);
            s_h[p * 70 + c] = (_Float16)(in ? fmaxf(a, 0.f) : 0.f);
        }
    }
    __syncthreads();

    const int ly = t >> 4, lx = t & 15;
    float sacc = c2b[0];
    #pragma unroll
    for (int t9 = 0; t9 < 9; t9++) {
        int pl = (ly + t9 / 3) * 18 + lx + (t9 % 3);
        const _Float16* rowp = s_h + pl * 70;
        const f16x2* wrow = c2wp + t9 * 32;
        #pragma unroll
        for (int cp = 0; cp < 32; cp++) {
            f16x2 hv = *(const f16x2*)&rowp[2 * cp];
            sacc = dot2h(hv, wrow[cp], sacc);
        }
    }
    long o = (long)img * HW + ((y0 + ly) << 8) + (x0 + lx);
    out0[o] = sacc + d2[o];
}

extern "C" void kernel_launch(void* const* d_in, const int* in_sizes, int n_in,
                              void* d_out, int out_size, void* d_ws, size_t ws_size,
                              hipStream_t stream)
{
    const float* origin   = (const float*)d_in[0];
    const float* residual = (const float*)d_in[1];
    const float* fxw1 = (const float*)d_in[2];  const float* fxb1 = (const float*)d_in[3];
    const float* fxw2 = (const float*)d_in[4];  const float* fxb2 = (const float*)d_in[5];
    const float* fxw3 = (const float*)d_in[6];  const float* fxb3 = (const float*)d_in[7];
    const float* fgw1 = (const float*)d_in[8];  const float* fgb1 = (const float*)d_in[9];
    const float* fgw2 = (const float*)d_in[10]; const float* fgb2 = (const float*)d_in[11];
    const float* fgw3 = (const float*)d_in[12]; const float* fgb3 = (const float*)d_in[13];
    const float* c1w  = (const float*)d_in[14]; const float* c1b  = (const float*)d_in[15];
    const float* c2w  = (const float*)d_in[16]; const float* c2b  = (const float*)d_in[17];

    float* out0 = (float*)d_out;                 // out = s + d
    float* out1 = out0 + (long)NB * HW;          // s (temp: packed bf16 x_/g_)
    float* out2 = out1 + (long)NB * HW;          // d
    bf16*  pack = (bf16*)out1;

    short* Bp2 = (short*)d_ws;                   // 20480 shorts
    short* Bp3 = Bp2 + 20480;                    // 110592 shorts
    f16x2* c1wp = (f16x2*)(Bp3 + 110592);        // 576 pairs
    f16x2* c2wp = c1wp + 576;                    // 288 pairs

    pack_all<<<516, 256, 0, stream>>>(fxw2, fgw2, fxw3, fgw3, c1w, c2w,
                                      Bp2, Bp3, c1wp, c2wp);

    branch_kernel<<<dim3(256, 16), 512, 0, stream>>>(
        origin, residual,
        fxw1, fxb1, fxb2, fxb3,
        fgw1, fgb1, fgb2, fgb3,
        Bp2, Bp3, pack, out2);

    tail_kernel<<<dim3(256, 8), 256, 0, stream>>>(pack, c1wp, c1b, c2wp, c2b, out2, out0);

    s_kernel<<<(NB * HW) / 256, 256, 0, stream>>>(out0, out2, out1);
}

// Round 20
// 239.365 us; speedup vs baseline: 1.1425x; 1.1425x over previous
//
#include <hip/hip_runtime.h>
#include <hip/hip_bf16.h>

typedef __hip_bfloat16 bf16;
typedef float f32x4 __attribute__((ext_vector_type(4)));
typedef short bf16x8 __attribute__((ext_vector_type(8)));
typedef _Float16 f16x2 __attribute__((ext_vector_type(2)));

#define HW 65536
#define NB 8

__device__ __forceinline__ bf16 f2b(float v){ return __float2bfloat16(v); }
__device__ __forceinline__ float b2f(bf16 v){ return __bfloat162float(v); }
__device__ __forceinline__ unsigned short fbits(float v){ bf16 b = f2b(v); return *(unsigned short*)&b; }
__device__ __forceinline__ unsigned int pk2(float a, float b){
    return (unsigned int)fbits(a) | ((unsigned int)fbits(b) << 16);
}
__device__ __forceinline__ float dot2h(f16x2 a, f16x2 b, float c){
#if __has_builtin(__builtin_amdgcn_fdot2)
    return __builtin_amdgcn_fdot2(a, b, c, false);
#else
    return c + (float)a[0]*(float)b[0] + (float)a[1]*(float)b[1];
#endif
}

// single merged pack kernel:
//  [0, 110592)          conv3 A-pack -> Bp3
//  [110592, 131072)     conv2 A-pack -> Bp2
//  [131072, 131936)     tail c1/c2 f16 pairing
__global__ void pack_all(const float* __restrict__ fxw2, const float* __restrict__ fgw2,
                         const float* __restrict__ fxw3, const float* __restrict__ fgw3,
                         const float* __restrict__ c1w,  const float* __restrict__ c2w,
                         short* __restrict__ Bp2, short* __restrict__ Bp3,
                         f16x2* __restrict__ c1wp, f16x2* __restrict__ c2wp)
{
    int idx = blockIdx.x * 256 + threadIdx.x;
    if (idx < 110592) {
        int unit = idx >> 9, r = idx & 511;
        int lane = r >> 3, j = r & 7;
        int mt = unit % 6; int u2 = unit / 6;
        int ks = u2 % 9;  int u3 = u2 / 9;
        int half = u3 & 1, br = u3 >> 1;
        int n = mt * 16 + (lane & 15);
        int c = half * 32 + ((lane >> 4) << 3) + j;
        const float* w = br ? fgw3 : fxw3;
        Bp3[idx] = fbits((n < 81) ? w[n * 576 + c * 9 + ks] : 0.f);
    } else if (idx < 131072) {
        int i = idx - 110592;
        int unit = i >> 9, r = i & 511;
        int lane = r >> 3, j = r & 7;
        int mt2 = unit & 1; int u2 = unit >> 1;
        int ks = u2 % 5; int u3 = u2 / 5;
        int half = u3 & 1, br = u3 >> 1;
        int n = half * 32 + mt2 * 16 + (lane & 15);
        int k = ks * 32 + ((lane >> 4) << 3) + j;
        int tap = k >> 4, c16 = k & 15;
        const float* w = br ? fgw2 : fxw2;
        Bp2[i] = fbits((tap < 9) ? w[n * 144 + c16 * 9 + tap] : 0.f);
    } else if (idx < 131936) {
        int i = idx - 131072;
        if (i < 576) {
            int c = i / 9, q = i - c * 9;
            c1wp[i] = (f16x2){(_Float16)c1w[c * 18 + q], (_Float16)c1w[c * 18 + 9 + q]};
        } else {
            int k = i - 576;
            int t9 = k >> 5, cp = k & 31;
            c2wp[k] = (f16x2){(_Float16)c2w[(2 * cp) * 9 + t9], (_Float16)c2w[(2 * cp + 1) * 9 + t9]};
        }
    }
}

__global__ void s_kernel(const float* __restrict__ out0, const float* __restrict__ d,
                         float* __restrict__ s)
{
    int i = blockIdx.x * 256 + threadIdx.x;
    s[i] = out0[i] - d[i];
}

// One dyn-filter branch per block: 16x16 output tile, 512 threads (8 waves).
// R19 + h2 DOUBLE-BUFFER phase overlap: conv2(0) | bar | {conv2(1), conv3(0)}
// | bar | conv3(1). The merged phase mixes conv2's LDS/MFMA work with conv3's
// L2 A-stream in one barrier-free region (counters show pipes were additive:
// 60 MFMA + 81 VALU + 65 LDS + 51 L2 ~= 245 measured).
// NOTE: no 2nd launch_bounds arg (R8/R13 mis-capped VGPRs).
__global__ __launch_bounds__(512) void branch_kernel(
    const float* __restrict__ origin, const float* __restrict__ residual,
    const float* __restrict__ fxw1, const float* __restrict__ fxb1,
    const float* __restrict__ fxb2, const float* __restrict__ fxb3,
    const float* __restrict__ fgw1, const float* __restrict__ fgb1,
    const float* __restrict__ fgb2, const float* __restrict__ fgb3,
    const short* __restrict__ Bp2, const short* __restrict__ Bp3,
    bf16* __restrict__ pack, float* __restrict__ dout)
{
    __shared__ bf16 s_srcb[648];      // 24x24 bf16 + 72 pad (gather never clamps)
    __shared__ bf16 s_h1[6720];       // [420 px][16ch], rows 400..419 zero (pads)
    __shared__ bf16 s_h2[2][12960];   // [324 px][40] ch-last (32 used), double-buffered
    __shared__ float s_sm2[1024];     // [mg][row16][col16][2] partial (ssum,fsum)

    const int t = threadIdx.x;
    const int lane = t & 63;
    const int w = t >> 6;             // wave 0..7
    const int mg = w >> 2;            // m-group: taps 48*mg..48*mg+47
    const int ng = w & 3;             // n-group: rows 4*ng..4*ng+3
    const int mt0 = 3 * mg;
    const int g = lane >> 4;
    const int j16 = lane & 15;
    const int tile = blockIdx.x;
    const int br = blockIdx.y >> 3;
    const int img = blockIdx.y & 7;
    const int y0 = (tile >> 4) << 4, x0 = (tile & 15) << 4;
    const long ib = (long)img * HW;

    const float* w1 = br ? fgw1 : fxw1;
    const float* b1 = br ? fgb1 : fxb1;
    const float* b2 = br ? fgb2 : fxb2;
    const float* b3 = br ? fgb3 : fxb3;

    // ---- phase 1: stage src (bf16, 648 incl. pad); g-branch materializes d ----
    for (int idx = t; idx < 648; idx += 512) {
        int sy = idx / 24, sx = idx - sy * 24;
        int gy = y0 - 4 + sy, gx = x0 - 4 + sx;
        float v = 0.f;
        if ((unsigned)gy < 256u && (unsigned)gx < 256u && idx < 576) {
            long o = ib + (gy << 8) + gx;
            if (br) { v = origin[o] - residual[o]; dout[o] = v; }
            else    { v = residual[o]; }
        }
        s_srcb[idx] = f2b(v);
    }
    __syncthreads();

    // ---- phase 2: conv1 (1->16) VALU -> h1 ch-last (stride 16); zero pad rows ----
    if (t < 400) {
        int p = t;
        int py = p / 20, px = p - py * 20;
        int gy = y0 - 2 + py, gx = x0 - 2 + px;
        bool in = (unsigned)gy < 256u && (unsigned)gx < 256u;
        float sw[9];
        #pragma unroll
        for (int dy = 0; dy < 3; dy++)
            #pragma unroll
            for (int dx = 0; dx < 3; dx++)
                sw[dy * 3 + dx] = b2f(s_srcb[(py + 1 + dy) * 24 + px + 1 + dx]);
        #pragma unroll
        for (int c = 0; c < 16; c++) {
            float a = b1[c];
            const float* wc = w1 + c * 9;
            #pragma unroll
            for (int q = 0; q < 9; q++) a = fmaf(wc[q], sw[q], a);
            s_h1[p * 16 + c] = f2b(in ? fmaxf(a, 0.f) : 0.f);
        }
    }
    for (int idx = t; idx < 320; idx += 512)
        s_h1[6400 + idx] = f2b(0.f);

    // ---- logits acc[3 m-tiles][4 n-tiles]; lane: taps (mt0+mi)*16+g*4+r, px (4ng+nr, j16) ----
    f32x4 acc[3][4];
    #pragma unroll
    for (int mi = 0; mi < 3; mi++) {
        int mt = mt0 + mi;
        f32x4 bv;
        if (mt < 5) {
            bv = *(const f32x4*)&b3[mt * 16 + (g << 2)];
        } else {
            float e0 = (g == 0) ? b3[80] : -1e30f;
            bv = (f32x4){e0, -1e30f, -1e30f, -1e30f};
        }
        #pragma unroll
        for (int nr = 0; nr < 4; nr++) acc[mi][nr] = bv;
    }
    __syncthreads();

    // conv2 for half h -> dsth2 (all 8 waves, 21 n-tiles)
    auto conv2_do = [&](int h, bf16* dsth2) {
        const short* Aw2 = Bp2 + (br * 2 + h) * 5120;
        bf16x8 A2[5][2];
        #pragma unroll
        for (int ks = 0; ks < 5; ks++)
            #pragma unroll
            for (int mt2 = 0; mt2 < 2; mt2++)
                A2[ks][mt2] = *(const bf16x8*)(Aw2 + ((ks * 2 + mt2) << 9) + lane * 8);
        const int kgh = g >> 1, c0 = (g & 1) * 8;
        for (int nt = w; nt < 21; nt += 8) {
            int p = nt * 16 + j16;
            int py = p / 18, px = p - py * 18;
            f32x4 acc2[2];
            #pragma unroll
            for (int mt2 = 0; mt2 < 2; mt2++)
                acc2[mt2] = *(const f32x4*)&b2[h * 32 + mt2 * 16 + (g << 2)];
            #pragma unroll
            for (int ks = 0; ks < 5; ks++) {
                int tap = 2 * ks + kgh;
                int ty = (tap * 11) >> 5;
                int tx = tap - ty * 3;
                int pl = (py + ty) * 20 + px + tx;   // <=419, pad rows zeroed
                bf16x8 B = *(const bf16x8*)&s_h1[pl * 16 + c0];
                #pragma unroll
                for (int mt2 = 0; mt2 < 2; mt2++)
                    acc2[mt2] = __builtin_amdgcn_mfma_f32_16x16x32_bf16(A2[ks][mt2], B, acc2[mt2], 0, 0, 0);
            }
            if (p < 324) {
                #pragma unroll
                for (int mt2 = 0; mt2 < 2; mt2++) {
                    unsigned int lo = pk2(fmaxf(acc2[mt2][0], 0.f), fmaxf(acc2[mt2][1], 0.f));
                    unsigned int hi = pk2(fmaxf(acc2[mt2][2], 0.f), fmaxf(acc2[mt2][3], 0.f));
                    *(uint2*)((char*)dsth2 + (p * 40 + mt2 * 16 + (g << 2)) * 2) = (uint2){lo, hi};
                }
            }
        }
    };

    // conv3 for half h from srch2 (wave: 3 m-tiles x 4 n-tiles, 1-deep A prefetch)
    auto conv3_do = [&](int h, const bf16* srch2) {
        const short* Aw3 = Bp3 + (br * 2 + h) * 27648;
        bf16x8 Acur[3], Anxt[3];
        #pragma unroll
        for (int mi = 0; mi < 3; mi++)
            Acur[mi] = *(const bf16x8*)(Aw3 + ((mt0 + mi) << 9) + lane * 8);
        #pragma unroll
        for (int ks = 0; ks < 9; ks++) {
            const int dy = (ks * 11) >> 5;
            const int dx = ks - dy * 3;
            if (ks < 8) {
                #pragma unroll
                for (int mi = 0; mi < 3; mi++)
                    Anxt[mi] = *(const bf16x8*)(Aw3 + (((ks + 1) * 6 + mt0 + mi) << 9) + lane * 8);
            }
            bf16x8 Bf[4];
            #pragma unroll
            for (int nr = 0; nr < 4; nr++) {
                int pl = (4 * ng + nr + dy) * 18 + j16 + dx;
                Bf[nr] = *(const bf16x8*)&srch2[pl * 40 + (g << 3)];
            }
            #pragma unroll
            for (int mi = 0; mi < 3; mi++)
                #pragma unroll
                for (int nr = 0; nr < 4; nr++)
                    acc[mi][nr] = __builtin_amdgcn_mfma_f32_16x16x32_bf16(Acur[mi], Bf[nr], acc[mi][nr], 0, 0, 0);
            #pragma unroll
            for (int mi = 0; mi < 3; mi++) Acur[mi] = Anxt[mi];
        }
    };

    // ---- phases 3/4 with overlap: conv2(0) | bar | conv2(1)+conv3(0) | bar | conv3(1) ----
    conv2_do(0, s_h2[0]);
    __syncthreads();
    conv2_do(1, s_h2[1]);     // LDS/MFMA work overlaps conv3(0)'s L2 A-stream
    conv3_do(0, s_h2[0]);
    __syncthreads();
    conv3_do(1, s_h2[1]);

    // ---- phase 5: softmax (NO max-pass) over 96 taps, split across 2 m-groups ----
    int toff[3][4];
    #pragma unroll
    for (int mi = 0; mi < 3; mi++)
        #pragma unroll
        for (int r = 0; r < 4; r++) {
            int tap = (mt0 + mi) * 16 + (g << 2) + r;
            int ti = (tap * 57) >> 9;                // tap/9 for tap<96
            toff[mi][r] = ti * 24 + (tap - ti * 9);
        }

    #pragma unroll
    for (int nr = 0; nr < 4; nr++) {
        int rb = (4 * ng + nr) * 16 + j16;
        float ss = 0.f, fs = 0.f;
        int base = (4 * ng + nr) * 24 + j16;
        #pragma unroll
        for (int mi = 0; mi < 3; mi++)
            #pragma unroll
            for (int r = 0; r < 4; r++) {
                float e = __expf(acc[mi][nr][r]);    // pads (-1e30) -> 0
                ss += e;
                fs += e * b2f(s_srcb[base + toff[mi][r]]);
            }
        ss += __shfl_xor(ss, 16);
        ss += __shfl_xor(ss, 32);
        fs += __shfl_xor(fs, 16);
        fs += __shfl_xor(fs, 32);
        if (g == 0) {
            s_sm2[(mg * 256 + rb) * 2]     = ss;
            s_sm2[(mg * 256 + rb) * 2 + 1] = fs;
        }
    }
    __syncthreads();

    // combine + store: waves 0..3 (mg==0), lane (g,j16) -> row 4*ng+g
    if (mg == 0) {
        int row = (ng << 2) + g;
        int rb = row * 16 + j16;
        float s0 = s_sm2[rb * 2],           f0 = s_sm2[rb * 2 + 1];
        float s1 = s_sm2[(256 + rb) * 2],   f1 = s_sm2[(256 + rb) * 2 + 1];
        pack[((long)(img * 2 + br) << 16) + ((y0 + row) << 8) + x0 + j16] = f2b((f0 + f1) / (s0 + s1));
    }
}

// c1(2->64)+c2(64->1) fused per tile via fp16 dot2; out0 = s + d
__global__ __launch_bounds__(256) void tail_kernel(
    const bf16* __restrict__ pack,
    const f16x2* __restrict__ c1wp, const float* __restrict__ c1b,
    const f16x2* __restrict__ c2wp, const float* __restrict__ c2b,
    const float* __restrict__ d2, float* __restrict__ out0)
{
    __shared__ f16x2 s_xg[400];            // 20x20 of (x_, g_)
    __shared__ _Float16 s_h[22680];        // [324][70] (64 used)

    const int t = threadIdx.x;
    const int tile = blockIdx.x;
    const int img = blockIdx.y;
    const int y0 = (tile >> 4) << 4, x0 = (tile & 15) << 4;

    for (int idx = t; idx < 400; idx += 256) {
        int hy = idx / 20, hx = idx - hy * 20;
        int gy = y0 - 2 + hy, gx = x0 - 2 + hx;
        float vx = 0.f, vg = 0.f;
        if ((unsigned)gy < 256u && (unsigned)gx < 256u) {
            int o = (gy << 8) + gx;
            vx = b2f(pack[((img * 2 + 0) << 16) + o]);
            vg = b2f(pack[((img * 2 + 1) << 16) + o]);
        }
        s_xg[idx] = (f16x2){(_Float16)vx, (_Float16)vg};
    }
    __syncthreads();

    for (int p = t; p < 324; p += 256) {
        int hy = p / 18, hx = p - hy * 18;
        int gy = y0 - 1 + hy, gx = x0 - 1 + hx;
        bool in = (unsigned)gy < 256u && (unsigned)gx < 256u;
        f16x2 sw[9];
        #pragma unroll
        for (int dy = 0; dy < 3; dy++)
            #pragma unroll
            for (int dx = 0; dx < 3; dx++)
                sw[dy * 3 + dx] = s_xg[(hy + dy) * 20 + hx + dx];
        for (int c = 0; c < 64; c++) {
            float a = c1b[c];
            const f16x2* wp = c1wp + c * 9;
            #pragma unroll
            for (int q = 0; q < 9; q++) a = dot2h(sw[q], wp[q], a);
            s_h[p * 70 + c] = (_Float16)(in ? fmaxf(a, 0.f) : 0.f);
        }
    }
    __syncthreads();

    const int ly = t >> 4, lx = t & 15;
    float sacc = c2b[0];
    #pragma unroll
    for (int t9 = 0; t9 < 9; t9++) {
        int pl = (ly + t9 / 3) * 18 + lx + (t9 % 3);
        const _Float16* rowp = s_h + pl * 70;
        const f16x2* wrow = c2wp + t9 * 32;
        #pragma unroll
        for (int cp = 0; cp < 32; cp++) {
            f16x2 hv = *(const f16x2*)&rowp[2 * cp];
            sacc = dot2h(hv, wrow[cp], sacc);
        }
    }
    long o = (long)img * HW + ((y0 + ly) << 8) + (x0 + lx);
    out0[o] = sacc + d2[o];
}

extern "C" void kernel_launch(void* const* d_in, const int* in_sizes, int n_in,
                              void* d_out, int out_size, void* d_ws, size_t ws_size,
                              hipStream_t stream)
{
    const float* origin   = (const float*)d_in[0];
    const float* residual = (const float*)d_in[1];
    const float* fxw1 = (const float*)d_in[2];  const float* fxb1 = (const float*)d_in[3];
    const float* fxw2 = (const float*)d_in[4];  const float* fxb2 = (const float*)d_in[5];
    const float* fxw3 = (const float*)d_in[6];  const float* fxb3 = (const float*)d_in[7];
    const float* fgw1 = (const float*)d_in[8];  const float* fgb1 = (const float*)d_in[9];
    const float* fgw2 = (const float*)d_in[10]; const float* fgb2 = (const float*)d_in[11];
    const float* fgw3 = (const float*)d_in[12]; const float* fgb3 = (const float*)d_in[13];
    const float* c1w  = (const float*)d_in[14]; const float* c1b  = (const float*)d_in[15];
    const float* c2w  = (const float*)d_in[16]; const float* c2b  = (const float*)d_in[17];

    float* out0 = (float*)d_out;                 // out = s + d
    float* out1 = out0 + (long)NB * HW;          // s (temp: packed bf16 x_/g_)
    float* out2 = out1 + (long)NB * HW;          // d
    bf16*  pack = (bf16*)out1;

    short* Bp2 = (short*)d_ws;                   // 20480 shorts
    short* Bp3 = Bp2 + 20480;                    // 110592 shorts
    f16x2* c1wp = (f16x2*)(Bp3 + 110592);        // 576 pairs
    f16x2* c2wp = c1wp + 576;                    // 288 pairs

    pack_all<<<516, 256, 0, stream>>>(fxw2, fgw2, fxw3, fgw3, c1w, c2w,
                                      Bp2, Bp3, c1wp, c2wp);

    branch_kernel<<<dim3(256, 16), 512, 0, stream>>>(
        origin, residual,
        fxw1, fxb1, fxb2, fxb3,
        fgw1, fgb1, fgb2, fgb3,
        Bp2, Bp3, pack, out2);

    tail_kernel<<<dim3(256, 8), 256, 0, stream>>>(pack, c1wp, c1b, c2wp, c2b, out2, out0);

    s_kernel<<<(NB * HW) / 256, 256, 0, stream>>>(out0, out2, out1);
}